// Round 1
// 1011.310 us; speedup vs baseline: 1.5505x; 1.5505x over previous
//
#include <hip/hip_runtime.h>
#include <math.h>

#define HH 1024
#define EE 512
#define VV 50257
#define BB 64
#define SS 1024
#define D2H 2048      // 2*H
#define KX 3584       // 2H + E + H
#define G4 4096       // 4H
#define PCH 16        // attention S-chunks per batch row (blocks per b)
#define SPLITK 8      // gates GEMM k-splits
#define KT_PER 14     // 112 k-tiles / SPLITK

// ---------------- K1: hb[b] = dot(hidden[b], We[2048:3072]) + be ----------------
__global__ void hb_kernel(const float* __restrict__ hidden, const float* __restrict__ We,
                          const float* __restrict__ be, float* __restrict__ hb) {
    int b = blockIdx.x;
    int t = threadIdx.x;                  // 256 threads, 4 floats each = 1024
    float4 hv = *(const float4*)(hidden + (size_t)b*HH + t*4);
    float4 wv = *(const float4*)(We + D2H + t*4);
    float pd = hv.x*wv.x + hv.y*wv.y + hv.z*wv.z + hv.w*wv.w;
    #pragma unroll
    for (int off = 32; off; off >>= 1) pd += __shfl_down(pd, off);
    __shared__ float red[4];
    int wave = t >> 6, lane = t & 63;
    if (lane == 0) red[wave] = pd;
    __syncthreads();
    if (t == 0) hb[b] = red[0] + red[1] + red[2] + red[3] + be[0];
}

// ---------------- K2: flash attention, wave-independent rows (no per-row barrier)
// Block = 4 waves; wave w owns 16 s-rows; lane owns dims {lane*4 + j*256 | j=0..7}.
__global__ __launch_bounds__(256) void attn_flash(
        const float* __restrict__ enc, const float* __restrict__ We,
        const float* __restrict__ hb,
        float* __restrict__ m_arr, float* __restrict__ l_arr, float* __restrict__ o_arr) {
    int chunk = blockIdx.x;   // 0..PCH-1
    int b     = blockIdx.y;   // 0..BB-1
    int t     = threadIdx.x;
    int lane  = t & 63, wave = t >> 6;

    float4 w[8];
    #pragma unroll
    for (int j = 0; j < 8; ++j) w[j] = *(const float4*)(We + lane*4 + j*256);
    float hbb = hb[b];

    const float* base = enc + ((size_t)b*SS + (size_t)chunk*64 + wave*16) * D2H + lane*4;

    float m = -INFINITY, l = 0.f;
    float4 o[8];
    #pragma unroll
    for (int j = 0; j < 8; ++j) o[j] = make_float4(0.f,0.f,0.f,0.f);

    float4 c[8], n[8];
    #pragma unroll
    for (int j = 0; j < 8; ++j) c[j] = *(const float4*)(base + j*256);

    for (int r = 0; r < 16; ++r) {
        if (r + 1 < 16) {
            const float* nb = base + (size_t)(r+1)*D2H;
            #pragma unroll
            for (int j = 0; j < 8; ++j) n[j] = *(const float4*)(nb + j*256);
        }
        float pd = 0.f;
        #pragma unroll
        for (int j = 0; j < 8; ++j)
            pd += c[j].x*w[j].x + c[j].y*w[j].y + c[j].z*w[j].z + c[j].w*w[j].w;
        #pragma unroll
        for (int off = 32; off; off >>= 1) pd += __shfl_xor(pd, off);
        float e  = fmaxf(pd + hbb, 0.f);          // ReLU energy
        float nm = fmaxf(m, e);
        float alpha = __expf(m - nm);
        float wt    = __expf(e - nm);
        l = l*alpha + wt;
        #pragma unroll
        for (int j = 0; j < 8; ++j) {
            o[j].x = o[j].x*alpha + wt*c[j].x;  o[j].y = o[j].y*alpha + wt*c[j].y;
            o[j].z = o[j].z*alpha + wt*c[j].z;  o[j].w = o[j].w*alpha + wt*c[j].w;
        }
        m = nm;
        #pragma unroll
        for (int j = 0; j < 8; ++j) c[j] = n[j];
    }

    // merge 4 waves' (m,l,o) once per block
    __shared__ float sm[4], sl[4];
    __shared__ float obuf[4][2048];
    if (lane == 0) { sm[wave] = m; sl[wave] = l; }
    __syncthreads();
    float M = fmaxf(fmaxf(sm[0], sm[1]), fmaxf(sm[2], sm[3]));
    float L = sl[0]*__expf(sm[0]-M) + sl[1]*__expf(sm[1]-M)
            + sl[2]*__expf(sm[2]-M) + sl[3]*__expf(sm[3]-M);
    float f = __expf(m - M);   // per-wave factor (m uniform within wave)
    #pragma unroll
    for (int j = 0; j < 8; ++j) {
        float4 v = o[j];
        v.x *= f; v.y *= f; v.z *= f; v.w *= f;
        *(float4*)&obuf[wave][lane*4 + j*256] = v;
    }
    __syncthreads();
    int p = b*PCH + chunk;
    if (t == 0) { m_arr[p] = M; l_arr[p] = L; }
    #pragma unroll
    for (int jj = 0; jj < 2; ++jj) {
        int d = lane*4 + (wave*2 + jj)*256;
        float4 s0 = *(float4*)&obuf[0][d];
        float4 s1 = *(float4*)&obuf[1][d];
        float4 s2 = *(float4*)&obuf[2][d];
        float4 s3 = *(float4*)&obuf[3][d];
        float4 r;
        r.x = s0.x+s1.x+s2.x+s3.x;  r.y = s0.y+s1.y+s2.y+s3.y;
        r.z = s0.z+s1.z+s2.z+s3.z;  r.w = s0.w+s1.w+s2.w+s3.w;
        *(float4*)(o_arr + (size_t)p*D2H + d) = r;
    }
}

// ------------- K3: combine partials -> c_i, build x_full = [c_i | emb | hidden] --
__global__ void attn_combine(const float* __restrict__ m_arr, const float* __restrict__ l_arr,
                             const float* __restrict__ o_arr,
                             const float* __restrict__ emb, const int* __restrict__ x_tok,
                             const float* __restrict__ hidden,
                             float* __restrict__ x_full) {
    int b = blockIdx.x;
    int t = threadIdx.x;  // 256
    float mv[PCH], f[PCH];
    float M = -INFINITY;
    #pragma unroll
    for (int p = 0; p < PCH; ++p) { mv[p] = m_arr[b*PCH + p]; M = fmaxf(M, mv[p]); }
    float L = 0.f;
    #pragma unroll
    for (int p = 0; p < PCH; ++p) { f[p] = __expf(mv[p] - M); L += l_arr[b*PCH + p] * f[p]; }
    float inv = 1.f / L;

    int d0 = t * 8;
    float4 a0 = {0,0,0,0}, a1 = {0,0,0,0};
    #pragma unroll
    for (int p = 0; p < PCH; ++p) {
        const float* op = o_arr + (size_t)(b*PCH + p) * D2H + d0;
        float4 v0 = *(const float4*)op;
        float4 v1 = *(const float4*)(op + 4);
        a0.x += v0.x*f[p]; a0.y += v0.y*f[p]; a0.z += v0.z*f[p]; a0.w += v0.w*f[p];
        a1.x += v1.x*f[p]; a1.y += v1.y*f[p]; a1.z += v1.z*f[p]; a1.w += v1.w*f[p];
    }
    a0.x *= inv; a0.y *= inv; a0.z *= inv; a0.w *= inv;
    a1.x *= inv; a1.y *= inv; a1.z *= inv; a1.w *= inv;
    float* xf = x_full + (size_t)b*KX + d0;
    *(float4*)xf       = a0;
    *(float4*)(xf + 4) = a1;

    // emb slice [2048:2560)
    int tok = x_tok[b];
    if (t < 128) {
        float4 v = *(const float4*)(emb + (size_t)tok*EE + t*4);
        *(float4*)(x_full + (size_t)b*KX + D2H + t*4) = v;
    }
    // hidden slice [2560:3584)
    float4 hv = *(const float4*)(hidden + (size_t)b*HH + t*4);
    *(float4*)(x_full + (size_t)b*KX + D2H + EE + t*4) = hv;
}

// ---------------- K4: split-K partial GEMM: gpart[s] = x_full @ W^T (k-chunk s) --
__global__ __launch_bounds__(256) void gates_gemm(
        const float* __restrict__ x_full,
        const float* __restrict__ W_ih, const float* __restrict__ W_hh,
        float* __restrict__ gpart) {
    __shared__ float Xs[32][68];
    __shared__ float Ws[32][68];
    int j0    = blockIdx.x * 64;
    int split = blockIdx.y;
    int t  = threadIdx.x;
    int tj = t & 15, tb = t >> 4;
    int vr = t >> 2, kq = t & 3;          // staging: row 0..63, k-quarter 0..3
    const int ks = split * KT_PER;
    int j = j0 + vr;
    const float* xrow = x_full + (size_t)vr * KX;
    float acc[4][4] = {};

    float4 xa, xb, wa, wb;
    auto LOADT = [&](int kt) {
        int k0 = kt*32 + kq*4;
        xa = *(const float4*)(xrow + k0);
        xb = *(const float4*)(xrow + k0 + 16);
        if (kt < 80) {
            const float* wrow = W_ih + (size_t)j*2560 + k0;
            wa = *(const float4*)(wrow);
            wb = *(const float4*)(wrow + 16);
        } else {
            const float* wrow = W_hh + (size_t)j*1024 + (kt-80)*32 + kq*4;
            wa = *(const float4*)(wrow);
            wb = *(const float4*)(wrow + 16);
        }
    };
    LOADT(ks);
    for (int i = 0; i < KT_PER; ++i) {
        int kr = kq * 4;
        Xs[kr+0][vr]=xa.x;  Xs[kr+1][vr]=xa.y;  Xs[kr+2][vr]=xa.z;  Xs[kr+3][vr]=xa.w;
        Xs[kr+16][vr]=xb.x; Xs[kr+17][vr]=xb.y; Xs[kr+18][vr]=xb.z; Xs[kr+19][vr]=xb.w;
        Ws[kr+0][vr]=wa.x;  Ws[kr+1][vr]=wa.y;  Ws[kr+2][vr]=wa.z;  Ws[kr+3][vr]=wa.w;
        Ws[kr+16][vr]=wb.x; Ws[kr+17][vr]=wb.y; Ws[kr+18][vr]=wb.z; Ws[kr+19][vr]=wb.w;
        if (i + 1 < KT_PER) LOADT(ks + i + 1);   // overlap next loads with compute
        __syncthreads();
        #pragma unroll
        for (int k = 0; k < 32; ++k) {
            float4 xv = *(const float4*)&Xs[k][tb*4];
            float4 wv = *(const float4*)&Ws[k][tj*4];
            float xaa[4] = {xv.x, xv.y, xv.z, xv.w};
            float waa[4] = {wv.x, wv.y, wv.z, wv.w};
            #pragma unroll
            for (int bi = 0; bi < 4; ++bi)
                #pragma unroll
                for (int ji = 0; ji < 4; ++ji)
                    acc[bi][ji] = fmaf(xaa[bi], waa[ji], acc[bi][ji]);
        }
        __syncthreads();
    }
    float* gp = gpart + (size_t)split * BB * G4;
    #pragma unroll
    for (int bi = 0; bi < 4; ++bi)
        #pragma unroll
        for (int ji = 0; ji < 4; ++ji) {
            int bb2 = tb*4 + bi;
            int jc  = j0 + tj*4 + ji;
            gp[(size_t)bb2*G4 + jc] = acc[bi][ji];
        }
}

// ---------------- K5: LSTM elementwise + split-K reduce + biases ----------------
__global__ void lstm_elem(const float* __restrict__ gpart,
                          const float* __restrict__ b_ih, const float* __restrict__ b_hh,
                          const float* __restrict__ cell,
                          float* __restrict__ h_out, float* __restrict__ c_out) {
    int idx = blockIdx.x * 256 + threadIdx.x;   // 0..65535
    int b = idx >> 10, hh = idx & 1023;
    float gi = b_ih[hh]      + b_hh[hh];
    float gf = b_ih[hh+1024] + b_hh[hh+1024];
    float gg = b_ih[hh+2048] + b_hh[hh+2048];
    float go = b_ih[hh+3072] + b_hh[hh+3072];
    #pragma unroll
    for (int s = 0; s < SPLITK; ++s) {
        const float* g = gpart + (size_t)s*BB*G4 + (size_t)b*G4;
        gi += g[hh]; gf += g[hh+1024]; gg += g[hh+2048]; go += g[hh+3072];
    }
    float si = 1.f / (1.f + __expf(-gi));
    float sf = 1.f / (1.f + __expf(-gf));
    float so = 1.f / (1.f + __expf(-go));
    float c  = sf * cell[idx] + si * tanhf(gg);
    float hn = so * tanhf(c);
    c_out[idx] = c;
    h_out[idx] = hn;
}

// ---------------- K6: predictions = h_next @ Wf^T + bf (pipelined staging) ------
__global__ __launch_bounds__(256) void proj_gemm(
        const float* __restrict__ h, const float* __restrict__ Wf,
        const float* __restrict__ bf, float* __restrict__ pred) {
    __shared__ float Hs[32][68];
    __shared__ float Ws[32][68];
    int v0 = blockIdx.x * 64;
    int t  = threadIdx.x;
    int tj = t & 15, tb = t >> 4;
    int vr = t >> 2, kq = t & 3;
    int v  = v0 + vr;
    bool wok = (v < VV);
    const float* hrow  = h  + (size_t)vr * HH;
    const float* wbase = Wf + (size_t)v  * HH;
    float acc[4][4] = {};

    float4 xa, xb, wa, wb;
    auto LOADT = [&](int kt) {
        int k0 = kt*32 + kq*4;
        xa = *(const float4*)(hrow + k0);
        xb = *(const float4*)(hrow + k0 + 16);
        if (wok) {
            wa = *(const float4*)(wbase + k0);
            wb = *(const float4*)(wbase + k0 + 16);
        } else {
            wa = make_float4(0.f,0.f,0.f,0.f);
            wb = make_float4(0.f,0.f,0.f,0.f);
        }
    };
    LOADT(0);
    for (int kt = 0; kt < 32; ++kt) {
        int kr = kq * 4;
        Hs[kr+0][vr]=xa.x;  Hs[kr+1][vr]=xa.y;  Hs[kr+2][vr]=xa.z;  Hs[kr+3][vr]=xa.w;
        Hs[kr+16][vr]=xb.x; Hs[kr+17][vr]=xb.y; Hs[kr+18][vr]=xb.z; Hs[kr+19][vr]=xb.w;
        Ws[kr+0][vr]=wa.x;  Ws[kr+1][vr]=wa.y;  Ws[kr+2][vr]=wa.z;  Ws[kr+3][vr]=wa.w;
        Ws[kr+16][vr]=wb.x; Ws[kr+17][vr]=wb.y; Ws[kr+18][vr]=wb.z; Ws[kr+19][vr]=wb.w;
        if (kt + 1 < 32) LOADT(kt + 1);
        __syncthreads();
        #pragma unroll
        for (int k = 0; k < 32; ++k) {
            float4 xv = *(const float4*)&Hs[k][tb*4];
            float4 wv = *(const float4*)&Ws[k][tj*4];
            float xaa[4] = {xv.x, xv.y, xv.z, xv.w};
            float waa[4] = {wv.x, wv.y, wv.z, wv.w};
            #pragma unroll
            for (int bi = 0; bi < 4; ++bi)
                #pragma unroll
                for (int ji = 0; ji < 4; ++ji)
                    acc[bi][ji] = fmaf(xaa[bi], waa[ji], acc[bi][ji]);
        }
        __syncthreads();
    }
    #pragma unroll
    for (int bi = 0; bi < 4; ++bi)
        #pragma unroll
        for (int ji = 0; ji < 4; ++ji) {
            int bb2 = tb*4 + bi;
            int vv  = v0 + tj*4 + ji;
            if (vv < VV) pred[(size_t)bb2*VV + vv] = acc[bi][ji] + bf[vv];
        }
}

extern "C" void kernel_launch(void* const* d_in, const int* in_sizes, int n_in,
                              void* d_out, int out_size, void* d_ws, size_t ws_size,
                              hipStream_t stream) {
    const float* enc    = (const float*)d_in[0];
    const int*   x_tok  = (const int*)  d_in[1];
    const float* hidden = (const float*)d_in[2];
    const float* cell   = (const float*)d_in[3];
    const float* emb    = (const float*)d_in[4];
    const float* We     = (const float*)d_in[5];
    const float* be     = (const float*)d_in[6];
    const float* W_ih   = (const float*)d_in[7];
    const float* W_hh   = (const float*)d_in[8];
    const float* b_ih   = (const float*)d_in[9];
    const float* b_hh   = (const float*)d_in[10];
    const float* Wf     = (const float*)d_in[11];
    const float* bf     = (const float*)d_in[12];

    float* out   = (float*)d_out;
    float* pred  = out;                               // B*V
    float* h_out = out + (size_t)BB * VV;             // B*H
    float* c_out = h_out + (size_t)BB * HH;           // B*H

    float* ws     = (float*)d_ws;
    float* hb     = ws;                               // 64
    float* m_arr  = ws + 64;                          // B*PCH = 1024
    float* l_arr  = m_arr + BB*PCH;                   // 1024
    float* o_arr  = l_arr + BB*PCH;                   // B*PCH*2048 = 2,097,152
    float* x_full = o_arr + (size_t)BB*PCH*D2H;       // B*KX = 229,376
    float* gpart  = x_full + (size_t)BB*KX;           // SPLITK*B*4H = 2,097,152
    // total ~17.7 MB of d_ws

    hb_kernel   <<<BB, 256, 0, stream>>>(hidden, We, be, hb);
    attn_flash  <<<dim3(PCH, BB), 256, 0, stream>>>(enc, We, hb, m_arr, l_arr, o_arr);
    attn_combine<<<BB, 256, 0, stream>>>(m_arr, l_arr, o_arr, emb, x_tok, hidden, x_full);
    gates_gemm  <<<dim3(G4/64, SPLITK), 256, 0, stream>>>(x_full, W_ih, W_hh, gpart);
    lstm_elem   <<<(BB*HH)/256, 256, 0, stream>>>(gpart, b_ih, b_hh, cell, h_out, c_out);
    proj_gemm   <<<(VV + 63)/64, 256, 0, stream>>>(h_out, Wf, bf, pred);
}